// Round 10
// baseline (181.421 us; speedup 1.0000x reference)
//
#include <hip/hip_runtime.h>

typedef unsigned short u16;
typedef unsigned int   u32;
typedef short bf8 __attribute__((ext_vector_type(8)));   // 8 bf16 payloads (4 VGPRs)
typedef float f4  __attribute__((ext_vector_type(4)));   // MFMA accumulator

#define NB   512
#define NJ   101
#define NM   50
#define NE   128
#define ND   60
#define NP   5120
#define NT   512
#define EPSV 1e-6f

// ---- LDS arena (byte offsets) ----
#define T_B    0        // tp -> attn bf16 [112][72] = 16128
#define C_B    16128    // cp bf16 [64][72] = 9216
#define H_B    25344    // hT bf16 [128][72] = 18432  (hT[e][m])
#define NT2_B  43776    // f32[112] sum tp^2 (written once per row, no atomics)
#define NC2_B  44224    // f32[64]  sum cp^2
#define MSK_B  44480    // u32[16]: per-wave 64-bit pad mask (lo,hi) x 8 waves
#define ARENA  44736

__device__ __forceinline__ u16 f2bh(float f) {
    return (u16)((__float_as_uint(f) + 0x8000u) >> 16);
}
__device__ __forceinline__ u32 pk2(float a, float b) {
    u32 ia = __float_as_uint(a) + 0x8000u;
    u32 ib = __float_as_uint(b) + 0x8000u;
    return (ia >> 16) | (ib & 0xFFFF0000u);
}
__device__ __forceinline__ bf8 pkfrag(float4 x, float4 y) {   // 8 f32 -> bf16 frag
    union { u32 u[4]; bf8 v; } r;
    r.u[0] = pk2(x.x, x.y); r.u[1] = pk2(x.z, x.w);
    r.u[2] = pk2(y.x, y.y); r.u[3] = pk2(y.z, y.w);
    return r.v;
}

// ===== Kernel A: W2T[e][k] = (R@Bc)[e][k]; rb2[e] = Bc_b.R[e] + R_b[e];
//       plus bf16 pre-conversion of At_w / Ac_w =====
__global__ __launch_bounds__(128) void w2_kernel(
    const float* __restrict__ Bc_w, const float* __restrict__ Bc_b,
    const float* __restrict__ R_w,  const float* __restrict__ R_b,
    const float* __restrict__ At_w, const float* __restrict__ Ac_w,
    u16* __restrict__ w2t, float* __restrict__ rb2,
    u16* __restrict__ atw, u16* __restrict__ acw)
{
    const int e = blockIdx.x, k = threadIdx.x;
    const float* Rrow = R_w + e * NE;
    float a0 = 0.f, a1 = 0.f, a2 = 0.f, a3 = 0.f;
    #pragma unroll 8
    for (int j = 0; j < NE; j += 4) {
        a0 += Rrow[j]     * Bc_w[j * NE + k];
        a1 += Rrow[j + 1] * Bc_w[(j + 1) * NE + k];
        a2 += Rrow[j + 2] * Bc_w[(j + 2) * NE + k];
        a3 += Rrow[j + 3] * Bc_w[(j + 3) * NE + k];
    }
    w2t[e * NE + k] = f2bh((a0 + a1) + (a2 + a3));
    if (e < ND) {
        atw[e * NE + k] = f2bh(At_w[e * NE + k]);
        acw[e * NE + k] = f2bh(Ac_w[e * NE + k]);
    }
    float c = Bc_b[k] * Rrow[k];
    for (int o = 32; o; o >>= 1) c += __shfl_xor(c, o, 64);
    __shared__ float part[2];
    if ((k & 63) == 0) part[k >> 6] = c;
    __syncthreads();
    if (k == 0) rb2[e] = part[0] + part[1] + R_b[e];
}

// tp full unit: wave exclusively owns rows jt*16..+15 -> register q-accum,
// single shuffle-reduce, plain store (no LDS atomics, no zero-init).
__device__ __forceinline__ void tp_full(int jt, int l15, int quad, const bf8* A,
    const u16* __restrict__ atw, const float* __restrict__ At_b,
    u16* __restrict__ tp16, float* __restrict__ nt2)
{
    float qa[4] = {0.f, 0.f, 0.f, 0.f};
    #pragma unroll
    for (int dt = 0; dt < 4; dt++) {
        const int d = dt * 16 + l15;
        const u16* arow = atw + (size_t)((d < ND) ? d : 0) * NE;
        float bv = (d < ND) ? At_b[d] : 0.f;
        f4 acc = {bv, bv, bv, bv};
        #pragma unroll
        for (int ks = 0; ks < 4; ks++)
            acc = __builtin_amdgcn_mfma_f32_16x16x32_bf16(
                A[ks], *(const bf8*)(arow + ks * 32 + quad * 8), acc, 0, 0, 0);
        const int j0 = jt * 16 + quad * 4;
        #pragma unroll
        for (int r = 0; r < 4; r++) {
            float v = acc[r];
            tp16[(j0 + r) * 72 + d] = (d < ND) ? f2bh(v) : (u16)0;
            qa[r] += (d < ND) ? v * v : 0.f;
        }
    }
    #pragma unroll
    for (int r = 0; r < 4; r++) {
        float q = qa[r];
        q += __shfl_xor(q, 1, 64); q += __shfl_xor(q, 2, 64);
        q += __shfl_xor(q, 4, 64); q += __shfl_xor(q, 8, 64);
        if (l15 == 0) nt2[jt * 16 + quad * 4 + r] = q;
    }
}

// cp full unit: wave exclusively owns rows mt*16..+15
__device__ __forceinline__ void cp_full(int mt, int l15, int quad, const bf8* Au,
    const u16* __restrict__ acw, const float* __restrict__ Ac_b,
    u16* __restrict__ cp16, float* __restrict__ nc2)
{
    float qa[4] = {0.f, 0.f, 0.f, 0.f};
    #pragma unroll
    for (int dt = 0; dt < 4; dt++) {
        const int d = dt * 16 + l15;
        const u16* arow = acw + (size_t)((d < ND) ? d : 0) * NE;
        float bv = (d < ND) ? Ac_b[d] : 0.f;
        f4 acc = {bv, bv, bv, bv};
        #pragma unroll
        for (int ks = 0; ks < 4; ks++)
            acc = __builtin_amdgcn_mfma_f32_16x16x32_bf16(
                Au[ks], *(const bf8*)(arow + ks * 32 + quad * 8), acc, 0, 0, 0);
        const int m0 = mt * 16 + quad * 4;
        #pragma unroll
        for (int r = 0; r < 4; r++) {
            float v = acc[r];
            cp16[(m0 + r) * 72 + d] = (d < ND) ? f2bh(v) : (u16)0;
            qa[r] += (d < ND) ? v * v : 0.f;
        }
    }
    #pragma unroll
    for (int r = 0; r < 4; r++) {
        float q = qa[r];
        q += __shfl_xor(q, 1, 64); q += __shfl_xor(q, 2, 64);
        q += __shfl_xor(q, 4, 64); q += __shfl_xor(q, 8, 64);
        if (l15 == 0) nc2[mt * 16 + quad * 4 + r] = q;
    }
}

// hT group: all 8 et tiles for one mt group; B = Au (gathered u rows mt*16+l15)
// hT[e][m] rows >=NM are finite garbage (clamped gather) -> zeroed by attn=0.
__device__ __forceinline__ void ht_group(int mtg, int l15, int quad, const bf8* Au,
    const u16* __restrict__ w2t, u16* __restrict__ hT16)
{
    #pragma unroll
    for (int et = 0; et < 8; et++) {
        const u16* wrow = w2t + (size_t)(et * 16 + l15) * NE;
        f4 acc = {0.f, 0.f, 0.f, 0.f};
        #pragma unroll
        for (int ks = 0; ks < 4; ks++)
            acc = __builtin_amdgcn_mfma_f32_16x16x32_bf16(
                *(const bf8*)(wrow + ks * 32 + quad * 8), Au[ks], acc, 0, 0, 0);
        const int e0 = et * 16 + quad * 4;
        #pragma unroll
        for (int r = 0; r < 4; r++)
            hT16[(e0 + r) * 72 + mtg * 16 + l15] = f2bh(acc[r]);
    }
}

// ===== Kernel B: R7 structure with the msk barrier removed (2 barriers) =====
// - pad mask: distributed scan in P0 (overlaps gather latency) -> 64-bit
//   register mask; per-wave shuffle-OR; lane0 -> 2 LDS words; P2 ORs 8 words.
//   Removes R7's zero-init + scatter + first barrier.
// - P3 stays DISTRIBUTED across all 8 waves behind the P2->P3 barrier
//   (R9's fusion regressed: wave-7 idle + serial softmax->P3 tail).
__global__ __launch_bounds__(NT, 2) void aitv_kernel(
    const int* __restrict__ titems, const int* __restrict__ citems,
    const int* __restrict__ pad_ids,
    const float* __restrict__ t_emb, const float* __restrict__ c_emb,
    const u16* __restrict__ atw,     const float* __restrict__ At_b,
    const u16* __restrict__ acw,     const float* __restrict__ Ac_b,
    const u16* __restrict__ w2t,     const float* __restrict__ rb2g,
    float* __restrict__ out)
{
    const int b    = blockIdx.x;
    const int t    = threadIdx.x;
    const int wid  = t >> 6;          // 0..7
    const int lane = t & 63;
    const int l15  = lane & 15;
    const int quad = lane >> 4;

    __shared__ __align__(16) char arena[ARENA];
    u16*   tp16 = (u16*)(arena + T_B);   u16* at16 = (u16*)(arena + T_B);
    u16*   cp16 = (u16*)(arena + C_B);
    u16*   hT16 = (u16*)(arena + H_B);
    float* nt2  = (float*)(arena + NT2_B);
    float* nc2  = (float*)(arena + NC2_B);
    u32*   mskw = (u32*)(arena + MSK_B);

    // ===== P0: issue ALL scattered gathers; pad-scan fills their latency =====
    float4 pxT[8];
    if (wid < 7) {
        int j = wid * 16 + l15; if (j > NJ - 1) j = NJ - 1;
        const float* vr = t_emb + (size_t)titems[b * NJ + j] * NE + quad * 8;
        #pragma unroll
        for (int h = 0; h < 8; h++)
            pxT[h] = *(const float4*)(vr + (h >> 1) * 32 + (h & 1) * 4);
    }
    const int mtu = wid & 3;                      // u-group this wave owns
    int mrow = mtu * 16 + l15; if (mrow > NM - 1) mrow = NM - 1;  // clamp: finite
    const float* vrU = c_emb + (size_t)citems[b * NM + mrow] * NE + quad * 8;
    float4 pxU[8];
    #pragma unroll
    for (int h = 0; h < 8; h++)
        pxU[h] = *(const float4*)(vrU + (h >> 1) * 32 + (h & 1) * 4);

    // distributed pad scan -> 64-bit register mask (no zero-init, no barrier)
    u32 mlo = 0, mhi = 0;
    for (int i = t; i < NP; i += NT)
        if (pad_ids[i] == b) {
            int pos = pad_ids[NP + i];
            if (pos < 32) mlo |= (1u << pos);
            else          mhi |= (1u << (pos - 32));
        }
    #pragma unroll
    for (int o = 1; o < 64; o <<= 1) {
        mlo |= __shfl_xor(mlo, o, 64);
        mhi |= __shfl_xor(mhi, o, 64);
    }
    if (lane == 0) { mskw[wid * 2] = mlo; mskw[wid * 2 + 1] = mhi; }

    // ===== P1: units (no preceding barrier) =====
    bf8 At[4];
    if (wid < 7) {
        #pragma unroll
        for (int ks = 0; ks < 4; ks++) At[ks] = pkfrag(pxT[2 * ks], pxT[2 * ks + 1]);
        tp_full(wid, l15, quad, At, atw, At_b, tp16, nt2);
    }
    bf8 Au[4];
    #pragma unroll
    for (int ks = 0; ks < 4; ks++) Au[ks] = pkfrag(pxU[2 * ks], pxU[2 * ks + 1]);
    if (wid < 4) ht_group(mtu, l15, quad, Au, w2t, hT16);
    else         cp_full(mtu, l15, quad, Au, acw, Ac_b, cp16, nc2);
    __syncthreads();                              // barrier 1 (P1 -> P2)

    // ===== P2: scores/softmax (waves 0..6, jt = wid) =====
    if (wid < 7) {
        const int jt = wid;
        u32 flo = 0, fhi = 0;
        #pragma unroll
        for (int w = 0; w < 8; w++) { flo |= mskw[w * 2]; fhi |= mskw[w * 2 + 1]; }

        f4 S[4];
        #pragma unroll
        for (int mt = 0; mt < 4; mt++) {
            f4 acc = {0.f, 0.f, 0.f, 0.f};
            #pragma unroll
            for (int ks = 0; ks < 2; ks++) {
                bf8 a  = *(const bf8*)(tp16 + (jt * 16 + l15) * 72 + ks * 32 + quad * 8);
                bf8 bb = *(const bf8*)(cp16 + (mt * 16 + l15) * 72 + ks * 32 + quad * 8);
                acc = __builtin_amdgcn_mfma_f32_16x16x32_bf16(a, bb, acc, 0, 0, 0);
            }
            S[mt] = acc;
        }
        bool valid[4]; float ncS[4];
        #pragma unroll
        for (int mt = 0; mt < 4; mt++) {
            int m = mt * 16 + l15;
            u32 bit = (m < 32) ? ((flo >> m) & 1u) : ((fhi >> (m - 32)) & 1u);
            valid[mt] = (m < NM) && (bit == 0u);
            ncS[mt]   = valid[mt] ? fmaxf(sqrtf(nc2[m]), EPSV) : 1.f;
        }
        #pragma unroll
        for (int r = 0; r < 4; r++) {
            int j = jt * 16 + quad * 4 + r;
            float ntj = fmaxf(sqrtf(nt2[j]), EPSV);
            float x[4], mx = -INFINITY;
            #pragma unroll
            for (int mt = 0; mt < 4; mt++) {
                x[mt] = valid[mt] ? S[mt][r] / (ntj * ncS[mt]) : -INFINITY;
                mx = fmaxf(mx, x[mt]);
            }
            mx = fmaxf(mx, __shfl_xor(mx, 1, 64)); mx = fmaxf(mx, __shfl_xor(mx, 2, 64));
            mx = fmaxf(mx, __shfl_xor(mx, 4, 64)); mx = fmaxf(mx, __shfl_xor(mx, 8, 64));
            float p[4], sm = 0.f;
            #pragma unroll
            for (int mt = 0; mt < 4; mt++) {
                p[mt] = valid[mt] ? __expf(x[mt] - mx) : 0.f;
                sm += p[mt];
            }
            sm += __shfl_xor(sm, 1, 64); sm += __shfl_xor(sm, 2, 64);
            sm += __shfl_xor(sm, 4, 64); sm += __shfl_xor(sm, 8, 64);
            float inv = (sm > 0.f) ? 1.f / sm : 0.f;
            #pragma unroll
            for (int mt = 0; mt < 4; mt++)
                at16[j * 72 + mt * 16 + l15] = f2bh(p[mt] * inv);
        }
    }
    __syncthreads();                              // barrier 2 (P2 -> P3)

    // ===== P3: out = attn @ hT^T + rb2 -> global f32 (56 units, 7/wave) =====
    for (int u = wid; u < 56; u += 8) {           // jt 0..6 x et 0..7, K=64
        int jt = u >> 3, et = u & 7;
        float bv = rb2g[et * 16 + l15];
        f4 acc = {bv, bv, bv, bv};
        #pragma unroll
        for (int ks = 0; ks < 2; ks++) {
            bf8 a  = *(const bf8*)(at16 + (jt * 16 + l15) * 72 + ks * 32 + quad * 8);
            bf8 bb = *(const bf8*)(hT16 + (et * 16 + l15) * 72 + ks * 32 + quad * 8);
            acc = __builtin_amdgcn_mfma_f32_16x16x32_bf16(a, bb, acc, 0, 0, 0);
        }
        int e = et * 16 + l15, j0 = jt * 16 + quad * 4;
        #pragma unroll
        for (int r = 0; r < 4; r++) {
            int j = j0 + r;
            if (j < NJ) out[((size_t)b * NJ + j) * NE + e] = acc[r];
        }
    }
}

extern "C" void kernel_launch(void* const* d_in, const int* in_sizes, int n_in,
                              void* d_out, int out_size, void* d_ws, size_t ws_size,
                              hipStream_t stream) {
    const int*   titems  = (const int*)d_in[0];
    const int*   citems  = (const int*)d_in[1];
    const int*   pad_ids = (const int*)d_in[2];
    const float* t_emb   = (const float*)d_in[3];
    const float* c_emb   = (const float*)d_in[4];
    const float* Ac_w    = (const float*)d_in[5];
    const float* Ac_b    = (const float*)d_in[6];
    const float* At_w    = (const float*)d_in[7];
    const float* At_b    = (const float*)d_in[8];
    const float* Bc_w    = (const float*)d_in[9];
    const float* Bc_b    = (const float*)d_in[10];
    const float* R_w     = (const float*)d_in[11];
    const float* R_b     = (const float*)d_in[12];
    float* out = (float*)d_out;

    u16*   w2t = (u16*)d_ws;                              // [128][128] bf16 = 32768B
    float* rb2 = (float*)((char*)d_ws + 32768);           // [128] f32 (512B)
    u16*   atw = (u16*)((char*)d_ws + 33280);             // [60][128] bf16 = 15360B
    u16*   acw = (u16*)((char*)d_ws + 48640);             // [60][128] bf16 = 15360B

    w2_kernel<<<NE, NE, 0, stream>>>(Bc_w, Bc_b, R_w, R_b, At_w, Ac_w,
                                     w2t, rb2, atw, acw);
    aitv_kernel<<<NB, NT, 0, stream>>>(titems, citems, pad_ids, t_emb, c_emb,
                                       atw, At_b, acw, Ac_b, w2t, rb2, out);
}

// Round 11
// 171.815 us; speedup vs baseline: 1.0559x; 1.0559x over previous
//
#include <hip/hip_runtime.h>

typedef unsigned short u16;
typedef unsigned int   u32;
typedef short bf8 __attribute__((ext_vector_type(8)));   // 8 bf16 payloads (4 VGPRs)
typedef float f4  __attribute__((ext_vector_type(4)));   // MFMA accumulator

#define NB   512
#define NJ   101
#define NM   50
#define NE   128
#define ND   60
#define NP   5120
#define NT   512
#define EPSV 1e-6f

// ---- LDS arena (byte offsets) ----
#define T_B    0        // tp -> attn bf16 [112][72] = 16128
#define C_B    16128    // cp bf16 [64][72] = 9216
#define H_B    25344    // hT bf16 [128][72] = 18432  (hT[e][m])
#define NT2_B  43776    // f32[112] sum tp^2 (written once per row, no atomics)
#define NC2_B  44224    // f32[64]  sum cp^2
#define MSK_B  44480    // int[64]
#define ARENA  44736

__device__ __forceinline__ u16 f2bh(float f) {
    return (u16)((__float_as_uint(f) + 0x8000u) >> 16);
}
__device__ __forceinline__ u32 pk2(float a, float b) {
    u32 ia = __float_as_uint(a) + 0x8000u;
    u32 ib = __float_as_uint(b) + 0x8000u;
    return (ia >> 16) | (ib & 0xFFFF0000u);
}
__device__ __forceinline__ bf8 pkfrag(float4 x, float4 y) {   // 8 f32 -> bf16 frag
    union { u32 u[4]; bf8 v; } r;
    r.u[0] = pk2(x.x, x.y); r.u[1] = pk2(x.z, x.w);
    r.u[2] = pk2(y.x, y.y); r.u[3] = pk2(y.z, y.w);
    return r.v;
}

// ===== Kernel A: W2T[e][k] = (R@Bc)[e][k]; rb2[e] = Bc_b.R[e] + R_b[e];
//       plus bf16 pre-conversion of At_w / Ac_w =====
__global__ __launch_bounds__(128) void w2_kernel(
    const float* __restrict__ Bc_w, const float* __restrict__ Bc_b,
    const float* __restrict__ R_w,  const float* __restrict__ R_b,
    const float* __restrict__ At_w, const float* __restrict__ Ac_w,
    u16* __restrict__ w2t, float* __restrict__ rb2,
    u16* __restrict__ atw, u16* __restrict__ acw)
{
    const int e = blockIdx.x, k = threadIdx.x;
    const float* Rrow = R_w + e * NE;
    float a0 = 0.f, a1 = 0.f, a2 = 0.f, a3 = 0.f;
    #pragma unroll 8
    for (int j = 0; j < NE; j += 4) {
        a0 += Rrow[j]     * Bc_w[j * NE + k];
        a1 += Rrow[j + 1] * Bc_w[(j + 1) * NE + k];
        a2 += Rrow[j + 2] * Bc_w[(j + 2) * NE + k];
        a3 += Rrow[j + 3] * Bc_w[(j + 3) * NE + k];
    }
    w2t[e * NE + k] = f2bh((a0 + a1) + (a2 + a3));
    if (e < ND) {
        atw[e * NE + k] = f2bh(At_w[e * NE + k]);
        acw[e * NE + k] = f2bh(Ac_w[e * NE + k]);
    }
    float c = Bc_b[k] * Rrow[k];
    for (int o = 32; o; o >>= 1) c += __shfl_xor(c, o, 64);
    __shared__ float part[2];
    if ((k & 63) == 0) part[k >> 6] = c;
    __syncthreads();
    if (k == 0) rb2[e] = part[0] + part[1] + R_b[e];
}

// tp full unit: wave exclusively owns rows jt*16..+15 -> register q-accum,
// single shuffle-reduce, plain store (no LDS atomics, no zero-init).
__device__ __forceinline__ void tp_full(int jt, int l15, int quad, const bf8* A,
    const u16* __restrict__ atw, const float* __restrict__ At_b,
    u16* __restrict__ tp16, float* __restrict__ nt2)
{
    float qa[4] = {0.f, 0.f, 0.f, 0.f};
    #pragma unroll
    for (int dt = 0; dt < 4; dt++) {
        const int d = dt * 16 + l15;
        const u16* arow = atw + (size_t)((d < ND) ? d : 0) * NE;
        float bv = (d < ND) ? At_b[d] : 0.f;
        f4 acc = {bv, bv, bv, bv};
        #pragma unroll
        for (int ks = 0; ks < 4; ks++)
            acc = __builtin_amdgcn_mfma_f32_16x16x32_bf16(
                A[ks], *(const bf8*)(arow + ks * 32 + quad * 8), acc, 0, 0, 0);
        const int j0 = jt * 16 + quad * 4;
        #pragma unroll
        for (int r = 0; r < 4; r++) {
            float v = acc[r];
            tp16[(j0 + r) * 72 + d] = (d < ND) ? f2bh(v) : (u16)0;
            qa[r] += (d < ND) ? v * v : 0.f;
        }
    }
    #pragma unroll
    for (int r = 0; r < 4; r++) {
        float q = qa[r];
        q += __shfl_xor(q, 1, 64); q += __shfl_xor(q, 2, 64);
        q += __shfl_xor(q, 4, 64); q += __shfl_xor(q, 8, 64);
        if (l15 == 0) nt2[jt * 16 + quad * 4 + r] = q;
    }
}

// cp full unit: wave exclusively owns rows mt*16..+15
__device__ __forceinline__ void cp_full(int mt, int l15, int quad, const bf8* Au,
    const u16* __restrict__ acw, const float* __restrict__ Ac_b,
    u16* __restrict__ cp16, float* __restrict__ nc2)
{
    float qa[4] = {0.f, 0.f, 0.f, 0.f};
    #pragma unroll
    for (int dt = 0; dt < 4; dt++) {
        const int d = dt * 16 + l15;
        const u16* arow = acw + (size_t)((d < ND) ? d : 0) * NE;
        float bv = (d < ND) ? Ac_b[d] : 0.f;
        f4 acc = {bv, bv, bv, bv};
        #pragma unroll
        for (int ks = 0; ks < 4; ks++)
            acc = __builtin_amdgcn_mfma_f32_16x16x32_bf16(
                Au[ks], *(const bf8*)(arow + ks * 32 + quad * 8), acc, 0, 0, 0);
        const int m0 = mt * 16 + quad * 4;
        #pragma unroll
        for (int r = 0; r < 4; r++) {
            float v = acc[r];
            cp16[(m0 + r) * 72 + d] = (d < ND) ? f2bh(v) : (u16)0;
            qa[r] += (d < ND) ? v * v : 0.f;
        }
    }
    #pragma unroll
    for (int r = 0; r < 4; r++) {
        float q = qa[r];
        q += __shfl_xor(q, 1, 64); q += __shfl_xor(q, 2, 64);
        q += __shfl_xor(q, 4, 64); q += __shfl_xor(q, 8, 64);
        if (l15 == 0) nc2[mt * 16 + quad * 4 + r] = q;
    }
}

// hT group: all 8 et tiles for one mt group; B = Au (gathered u rows mt*16+l15)
// hT[e][m] rows >=NM are finite garbage (clamped gather) -> zeroed by attn=0.
__device__ __forceinline__ void ht_group(int mtg, int l15, int quad, const bf8* Au,
    const u16* __restrict__ w2t, u16* __restrict__ hT16)
{
    #pragma unroll
    for (int et = 0; et < 8; et++) {
        const u16* wrow = w2t + (size_t)(et * 16 + l15) * NE;
        f4 acc = {0.f, 0.f, 0.f, 0.f};
        #pragma unroll
        for (int ks = 0; ks < 4; ks++)
            acc = __builtin_amdgcn_mfma_f32_16x16x32_bf16(
                *(const bf8*)(wrow + ks * 32 + quad * 8), Au[ks], acc, 0, 0, 0);
        const int e0 = et * 16 + quad * 4;
        #pragma unroll
        for (int r = 0; r < 4; r++)
            hT16[(e0 + r) * 72 + mtg * 16 + l15] = f2bh(acc[r]);
    }
}

// ===== Kernel B (R7 verified optimum, exact restore): 8 waves, grid 512 =====
// All scattered gathers (t-rows AND u-rows) issued in P0 before the first
// barrier -> one memory-latency round. Distributed LDS-scatter pad scan in P1.
// NOTE: R9/R10 measured the register-bitmask scan variant at 51-52us vs this
// structure's 43us (serial shuffle-OR chain + lost phase-sync regressed it).
__global__ __launch_bounds__(NT, 2) void aitv_kernel(
    const int* __restrict__ titems, const int* __restrict__ citems,
    const int* __restrict__ pad_ids,
    const float* __restrict__ t_emb, const float* __restrict__ c_emb,
    const u16* __restrict__ atw,     const float* __restrict__ At_b,
    const u16* __restrict__ acw,     const float* __restrict__ Ac_b,
    const u16* __restrict__ w2t,     const float* __restrict__ rb2g,
    float* __restrict__ out)
{
    const int b    = blockIdx.x;
    const int t    = threadIdx.x;
    const int wid  = t >> 6;          // 0..7
    const int lane = t & 63;
    const int l15  = lane & 15;
    const int quad = lane >> 4;

    __shared__ __align__(16) char arena[ARENA];
    u16*   tp16 = (u16*)(arena + T_B);   u16* at16 = (u16*)(arena + T_B);
    u16*   cp16 = (u16*)(arena + C_B);
    u16*   hT16 = (u16*)(arena + H_B);
    float* nt2  = (float*)(arena + NT2_B);
    float* nc2  = (float*)(arena + NC2_B);
    int*   msk  = (int*)(arena + MSK_B);

    // ===== P0: issue ALL gathers (t-rows w0..6; u-rows all waves); zero msk =====
    float4 pxT[8];
    if (wid < 7) {
        int j = wid * 16 + l15; if (j > NJ - 1) j = NJ - 1;
        const float* vr = t_emb + (size_t)titems[b * NJ + j] * NE + quad * 8;
        #pragma unroll
        for (int h = 0; h < 8; h++)
            pxT[h] = *(const float4*)(vr + (h >> 1) * 32 + (h & 1) * 4);
    }
    const int mtu = wid & 3;                      // u-group this wave owns
    int mrow = mtu * 16 + l15; if (mrow > NM - 1) mrow = NM - 1;  // clamp: finite
    const float* vrU = c_emb + (size_t)citems[b * NM + mrow] * NE + quad * 8;
    float4 pxU[8];
    #pragma unroll
    for (int h = 0; h < 8; h++)
        pxU[h] = *(const float4*)(vrU + (h >> 1) * 32 + (h & 1) * 4);

    if (t < 64) msk[t] = 0;
    __syncthreads();

    // ===== P1: pad-scan covers gather-latency tail; then units =====
    for (int i = t; i < NP; i += NT)
        if (pad_ids[i] == b) msk[pad_ids[NP + i]] = 1;

    bf8 At[4];
    if (wid < 7) {
        #pragma unroll
        for (int ks = 0; ks < 4; ks++) At[ks] = pkfrag(pxT[2 * ks], pxT[2 * ks + 1]);
        tp_full(wid, l15, quad, At, atw, At_b, tp16, nt2);
    }
    bf8 Au[4];
    #pragma unroll
    for (int ks = 0; ks < 4; ks++) Au[ks] = pkfrag(pxU[2 * ks], pxU[2 * ks + 1]);
    if (wid < 4) ht_group(mtu, l15, quad, Au, w2t, hT16);
    else         cp_full(mtu, l15, quad, Au, acw, Ac_b, cp16, nc2);
    __syncthreads();

    // ===== P2: scores/softmax (waves 0..6, jt = wid) =====
    if (wid < 7) {
        const int jt = wid;
        f4 S[4];
        #pragma unroll
        for (int mt = 0; mt < 4; mt++) {
            f4 acc = {0.f, 0.f, 0.f, 0.f};
            #pragma unroll
            for (int ks = 0; ks < 2; ks++) {
                bf8 a  = *(const bf8*)(tp16 + (jt * 16 + l15) * 72 + ks * 32 + quad * 8);
                bf8 bb = *(const bf8*)(cp16 + (mt * 16 + l15) * 72 + ks * 32 + quad * 8);
                acc = __builtin_amdgcn_mfma_f32_16x16x32_bf16(a, bb, acc, 0, 0, 0);
            }
            S[mt] = acc;
        }
        bool valid[4]; float ncS[4];
        #pragma unroll
        for (int mt = 0; mt < 4; mt++) {
            int m = mt * 16 + l15;
            valid[mt] = (m < NM) && (msk[m] == 0);
            ncS[mt]   = valid[mt] ? fmaxf(sqrtf(nc2[m]), EPSV) : 1.f;
        }
        #pragma unroll
        for (int r = 0; r < 4; r++) {
            int j = jt * 16 + quad * 4 + r;
            float ntj = fmaxf(sqrtf(nt2[j]), EPSV);
            float x[4], mx = -INFINITY;
            #pragma unroll
            for (int mt = 0; mt < 4; mt++) {
                x[mt] = valid[mt] ? S[mt][r] / (ntj * ncS[mt]) : -INFINITY;
                mx = fmaxf(mx, x[mt]);
            }
            mx = fmaxf(mx, __shfl_xor(mx, 1, 64)); mx = fmaxf(mx, __shfl_xor(mx, 2, 64));
            mx = fmaxf(mx, __shfl_xor(mx, 4, 64)); mx = fmaxf(mx, __shfl_xor(mx, 8, 64));
            float p[4], sm = 0.f;
            #pragma unroll
            for (int mt = 0; mt < 4; mt++) {
                p[mt] = valid[mt] ? __expf(x[mt] - mx) : 0.f;
                sm += p[mt];
            }
            sm += __shfl_xor(sm, 1, 64); sm += __shfl_xor(sm, 2, 64);
            sm += __shfl_xor(sm, 4, 64); sm += __shfl_xor(sm, 8, 64);
            float inv = (sm > 0.f) ? 1.f / sm : 0.f;
            #pragma unroll
            for (int mt = 0; mt < 4; mt++)
                at16[j * 72 + mt * 16 + l15] = f2bh(p[mt] * inv);
        }
    }
    __syncthreads();

    // ===== P3: out = attn @ hT^T + rb2 -> global f32 (56 units, 7/wave) =====
    for (int u = wid; u < 56; u += 8) {           // jt 0..6 x et 0..7, K=64
        int jt = u >> 3, et = u & 7;
        float bv = rb2g[et * 16 + l15];
        f4 acc = {bv, bv, bv, bv};
        #pragma unroll
        for (int ks = 0; ks < 2; ks++) {
            bf8 a  = *(const bf8*)(at16 + (jt * 16 + l15) * 72 + ks * 32 + quad * 8);
            bf8 bb = *(const bf8*)(hT16 + (et * 16 + l15) * 72 + ks * 32 + quad * 8);
            acc = __builtin_amdgcn_mfma_f32_16x16x32_bf16(a, bb, acc, 0, 0, 0);
        }
        int e = et * 16 + l15, j0 = jt * 16 + quad * 4;
        #pragma unroll
        for (int r = 0; r < 4; r++) {
            int j = j0 + r;
            if (j < NJ) out[((size_t)b * NJ + j) * NE + e] = acc[r];
        }
    }
}

extern "C" void kernel_launch(void* const* d_in, const int* in_sizes, int n_in,
                              void* d_out, int out_size, void* d_ws, size_t ws_size,
                              hipStream_t stream) {
    const int*   titems  = (const int*)d_in[0];
    const int*   citems  = (const int*)d_in[1];
    const int*   pad_ids = (const int*)d_in[2];
    const float* t_emb   = (const float*)d_in[3];
    const float* c_emb   = (const float*)d_in[4];
    const float* Ac_w    = (const float*)d_in[5];
    const float* Ac_b    = (const float*)d_in[6];
    const float* At_w    = (const float*)d_in[7];
    const float* At_b    = (const float*)d_in[8];
    const float* Bc_w    = (const float*)d_in[9];
    const float* Bc_b    = (const float*)d_in[10];
    const float* R_w     = (const float*)d_in[11];
    const float* R_b     = (const float*)d_in[12];
    float* out = (float*)d_out;

    u16*   w2t = (u16*)d_ws;                              // [128][128] bf16 = 32768B
    float* rb2 = (float*)((char*)d_ws + 32768);           // [128] f32 (512B)
    u16*   atw = (u16*)((char*)d_ws + 33280);             // [60][128] bf16 = 15360B
    u16*   acw = (u16*)((char*)d_ws + 48640);             // [60][128] bf16 = 15360B

    w2_kernel<<<NE, NE, 0, stream>>>(Bc_w, Bc_b, R_w, R_b, At_w, Ac_w,
                                     w2t, rb2, atw, acw);
    aitv_kernel<<<NB, NT, 0, stream>>>(titems, citems, pad_ids, t_emb, c_emb,
                                       atw, At_b, acw, Ac_b, w2t, rb2, out);
}